// Round 14
// baseline (90.588 us; speedup 1.0000x reference)
//
#include <hip/hip_runtime.h>
#include <hip/hip_bf16.h>
#include <stdint.h>

#define NE 8
#define DK 1024
#define FN 1024
#define NTOK 8192

#define BN 128
#define BK 64
#define NIT (DK / BK)
#define H 80             // per-wave rows (2 M-waves -> 160-row region)

#define HB 32
#define EPB (NTOK * 2 / HB)

// LDS map per buffer (per 256-thread block): A [160 rows x 128B] @0 (20480B),
// B-kh0 @20480 (8192B), B-kh1 @28672 (8192B); buffer 36864B x2 = 72KB.
// => 2 blocks/CU (144KB <= 160KB), independent barrier domains.
#define BUFS 36864
#define BOFF 20480

#define GATE_BLOCKS (NTOK / 4)                       // 2048
#define CONV_BLOCKS (NE * FN * DK / 8 / 256)         // 4096 (32B/thread)

typedef __attribute__((ext_vector_type(4))) float f32x4;
typedef __attribute__((ext_vector_type(8))) short short8;
typedef __attribute__((ext_vector_type(4))) short short4v;

__device__ __forceinline__ unsigned short f2bf(float f) {
    union { float f; unsigned u; } v; v.f = f;
    unsigned r = v.u;
    unsigned lsb = (r >> 16) & 1u;
    r += 0x7fffu + lsb;
    return (unsigned short)(r >> 16);
}
__device__ __forceinline__ float bf2f(unsigned short u) {
    union { unsigned u; float f; } v; v.u = ((unsigned)u) << 16;
    return v.f;
}

// ---------------- fused: gating + x->bf16  |  W->bf16  (one launch) ----------
__global__ __launch_bounds__(256) void k_prep(const float* __restrict__ x,
    const float* __restrict__ Wg, const float* __restrict__ bg,
    const float* __restrict__ W,
    unsigned short* __restrict__ xb, unsigned short* __restrict__ Wb,
    int* __restrict__ meta_e, float* __restrict__ meta_w)
{
    if (blockIdx.x >= GATE_BLOCKS) {
        int i = ((blockIdx.x - GATE_BLOCKS) * 256 + threadIdx.x) * 2;
#pragma unroll
        for (int q = 0; q < 2; ++q) {
            f32x4 v = ((const f32x4*)W)[i + q];
            short4v b;
            b.x = (short)f2bf(v.x); b.y = (short)f2bf(v.y);
            b.z = (short)f2bf(v.z); b.w = (short)f2bf(v.w);
            ((short4v*)Wb)[i + q] = b;
        }
        return;
    }

    const int lane = threadIdx.x & 63;
    const int t = blockIdx.x * 4 + (threadIdx.x >> 6);

    const f32x4* xr = (const f32x4*)(x + (size_t)t * DK);
    f32x4 xv[4];
#pragma unroll
    for (int c = 0; c < 4; ++c) xv[c] = xr[lane + 64 * c];

    short4v* xbo = (short4v*)(xb + (size_t)t * DK);
#pragma unroll
    for (int c = 0; c < 4; ++c) {
        short4v b;
        b.x = (short)f2bf(xv[c].x); b.y = (short)f2bf(xv[c].y);
        b.z = (short)f2bf(xv[c].z); b.w = (short)f2bf(xv[c].w);
        xbo[lane + 64 * c] = b;
    }

    float acc[NE];
#pragma unroll
    for (int e = 0; e < NE; ++e) {
        const f32x4* wr = (const f32x4*)(Wg + e * DK);
        float a = 0.f;
#pragma unroll
        for (int c = 0; c < 4; ++c) {
            f32x4 wv = wr[lane + 64 * c];
            a += xv[c].x * wv.x + xv[c].y * wv.y + xv[c].z * wv.z + xv[c].w * wv.w;
        }
        acc[e] = a;
    }
#pragma unroll
    for (int e = 0; e < NE; ++e) {
        float a = acc[e];
#pragma unroll
        for (int off = 32; off > 0; off >>= 1) a += __shfl_xor(a, off, 64);
        acc[e] = a;
    }
    if (lane == 0) {
        float v[NE];
#pragma unroll
        for (int e = 0; e < NE; ++e) v[e] = acc[e] + bg[e];
        int b0 = 0; float m0 = v[0];
#pragma unroll
        for (int e = 1; e < NE; ++e) if (v[e] > m0) { m0 = v[e]; b0 = e; }
        int b1 = -1; float m1 = -3.4e38f;
#pragma unroll
        for (int e = 0; e < NE; ++e) if (e != b0 && v[e] > m1) { m1 = v[e]; b1 = e; }
        float r = expf(m1 - m0);
        float s = 1.f + r;
        meta_e[2 * t] = b0; meta_e[2 * t + 1] = b1;
        meta_w[2 * t] = 1.f / s; meta_w[2 * t + 1] = r / s;
    }
}

// ---------------- per-block histogram (LDS atomics only) ---------------------
__global__ __launch_bounds__(256) void k_hist(const int* __restrict__ meta_e,
                                              int* __restrict__ blockcnt)
{
    __shared__ int lh[NE];
    if (threadIdx.x < NE) lh[threadIdx.x] = 0;
    __syncthreads();
    int base = blockIdx.x * EPB;
#pragma unroll
    for (int k = 0; k < EPB / 256; ++k)
        atomicAdd(&lh[meta_e[base + k * 256 + threadIdx.x]], 1);
    __syncthreads();
    if (threadIdx.x < NE) blockcnt[blockIdx.x * NE + threadIdx.x] = lh[threadIdx.x];
}

// ---------------- scatter with inline scan ----------------------------------
__global__ __launch_bounds__(256) void k_scatter(const int* __restrict__ meta_e,
    const float* __restrict__ meta_w, const int* __restrict__ blockcnt,
    int* __restrict__ seg, int* __restrict__ ridx, float* __restrict__ rw)
{
    __shared__ int lh[NE];
    __shared__ int bb[NE];
    __shared__ int colsum[NE];
    __shared__ int segstart[NE];
    int tid = threadIdx.x;
    if (tid < NE) {
        lh[tid] = 0;
        int run = 0, mypre = 0;
        for (int b = 0; b < HB; ++b) {
            if (b == (int)blockIdx.x) mypre = run;
            run += blockcnt[b * NE + tid];
        }
        colsum[tid] = run;
        bb[tid] = mypre;
    }
    __syncthreads();
    if (tid == 0) {
        int s = 0;
        for (int e = 0; e < NE; ++e) { segstart[e] = s; s += colsum[e]; }
        if (blockIdx.x == 0) {
            int s2 = 0;
            for (int e = 0; e < NE; ++e) { seg[e] = s2; s2 += colsum[e]; }
            seg[NE] = s2;
        }
    }
    __syncthreads();
    if (tid < NE) bb[tid] += segstart[tid];
    __syncthreads();
    int bs = blockIdx.x * EPB;
#pragma unroll
    for (int k = 0; k < EPB / 256; ++k) {
        int i = bs + k * 256 + tid;
        int e = meta_e[i];
        int r = atomicAdd(&lh[e], 1);
        int p = bb[e] + r;
        ridx[p] = i;
        rw[p] = meta_w[i];
    }
}

// ---------------- grouped GEMM: 256-thr blocks, 2/CU, R8 2-gate schedule -----
// 4 waves (2M x 2N), per-wave 80x64, acc[5][4]=80 AGPR (~190 regs/wave ->
// 2 blocks/SIMD-pair fit: 380<=512). Grid = 8e x 8n x 16mt = 1024 = 4/CU,
// balanced (lpt = ceil(L/16) <= 160). Two resident blocks have INDEPENDENT
// barriers -> one block's MFMA hides the other's gate/stage stalls (m114).
// Stage groups/tile: [A:5][B0:2][B1:2] = 9 outstanding, same as R8-R13 ->
// gate constants and vmcnt in-order-retire proof carry over:
//   GATE(2) @kk0: outstanding A(t)5+B0(t)2+B1(t)2=9 -> retires A+B0.
//   GATE(7) @kk1: outstanding B1(t)2+A(t+1)5+B0(t+1)2=9 -> retires B1(t).
//   Last tile GATE(0). WAR: lgkm0 before MFMAs -> reads done before next
//   barrier; stages target buf^1 (disjoint).
// Swizzle invariants (re-derived): A staging rows c*32+(tid>>3) -> perm
// (row&7)=((tid>>3)&7); B rows c*64+(tid>>2) -> perm ((row>>1)&3)=((tid>>3)&3);
// read side unchanged.
template <int MODE>
__global__ __launch_bounds__(256, 2) void k_gemm(const unsigned short* __restrict__ xb,
    const unsigned short* __restrict__ Wb, const float* __restrict__ be,
    const int* __restrict__ seg, const int* __restrict__ ridx,
    const float* __restrict__ rw, float* __restrict__ out, void* __restrict__ ywv)
{
    __shared__ char Lds[2 * BUFS];   // 72 KB

    const int bid = blockIdx.x;
    const int e = bid & 7;                       // XCD-pinned expert
    const int n0 = ((bid >> 3) & 7) * BN;
    const int mt = bid >> 6;                     // 0..15
    const int s0 = seg[e];
    const int L = seg[e + 1] - s0;
    const int lpt = (L + 15) >> 4;               // rows per m-tile
    int m0 = mt * lpt;
    const int m_end = (m0 + lpt < L) ? (m0 + lpt) : L;
    if (m0 >= m_end) return;

    const int tid = threadIdx.x;
    const int lane = tid & 63;
    const int wid = tid >> 6;
    const int wm = wid >> 1, wn = wid & 1;       // 2 x 2 wave grid
    const int frow = lane & 15;
    const int fq = lane >> 4;

    // B staging offsets (32-bit elements off Wb): instr c covers rows c*64+tid/4
    const int bgr = ((tid & 3) ^ ((tid >> 3) & 3)) * 8;
    unsigned boff[2];
#pragma unroll
    for (int c = 0; c < 2; ++c)
        boff[c] = (((unsigned)(e * FN + n0 + c * 64 + (tid >> 2))) << 10) + bgr;

    // read bases
    int b_base[2];
    {
        int r = wn * 64 + frow;
        int sl = fq ^ ((frow >> 1) & 3);
#pragma unroll
        for (int kk = 0; kk < 2; ++kk)
            b_base[kk] = BOFF + kk * 8192 + r * 64 + sl * 16;
    }
    int a_base[2];
#pragma unroll
    for (int kk = 0; kk < 2; ++kk)
        a_base[kk] = (wm * H + frow) * 128 + (((kk * 4 + fq) ^ (frow & 7)) * 16);

    char* LB = (char*)Lds;
    const int ag = ((tid & 7) ^ ((tid >> 3) & 7)) * 8;

    // chunk loop (single iteration unless an expert holds >2560 rows)
    for (; m0 < m_end; m0 += 160) {
        // A staging offsets: instr c covers rows c*32 + tid/8 (clamped)
        unsigned aoff[5];
#pragma unroll
        for (int c = 0; c < 5; ++c) {
            int r = c * 32 + (tid >> 3);
            int idx = m0 + r; if (idx >= m_end) idx = m_end - 1;
            aoff[c] = (((unsigned)(ridx[s0 + idx] >> 1)) << 10) + ag;
        }

        f32x4 acc[5][4];
#pragma unroll
        for (int i = 0; i < 5; ++i)
#pragma unroll
            for (int j = 0; j < 4; ++j) acc[i][j] = f32x4{0.f, 0.f, 0.f, 0.f};

        auto STAGE_A = [&](int buf, int kt) {
            const unsigned ko = kt * BK;
            char* dst = LB + buf * BUFS + wid * 1024;
#pragma unroll
            for (int c = 0; c < 5; ++c)
                __builtin_amdgcn_global_load_lds(
                    (const __attribute__((address_space(1))) void*)(xb + aoff[c] + ko),
                    (__attribute__((address_space(3))) void*)(dst + c * 4096), 16, 0, 0);
        };
        auto STAGE_B = [&](int buf, int kt, int kh) {
            const unsigned ko = kt * BK + kh * 32;
            char* dst = LB + buf * BUFS + BOFF + kh * 8192 + wid * 1024;
#pragma unroll
            for (int c = 0; c < 2; ++c)
                __builtin_amdgcn_global_load_lds(
                    (const __attribute__((address_space(1))) void*)(Wb + boff[c] + ko),
                    (__attribute__((address_space(3))) void*)(dst + c * 4096), 16, 0, 0);
        };

#define GATE(N) do { asm volatile("s_waitcnt vmcnt(" #N ")" ::: "memory"); \
                     __builtin_amdgcn_s_barrier(); \
                     __builtin_amdgcn_sched_barrier(0); } while (0)
#define LGKM0 do { asm volatile("s_waitcnt lgkmcnt(0)" ::: "memory"); \
                   __builtin_amdgcn_sched_barrier(0); } while (0)
#define MFMA20(AF, BF) do { \
    __builtin_amdgcn_s_setprio(1); \
    _Pragma("unroll") \
    for (int mi = 0; mi < 5; ++mi) { \
        _Pragma("unroll") \
        for (int ni = 0; ni < 4; ++ni) \
            acc[mi][ni] = __builtin_amdgcn_mfma_f32_16x16x32_bf16( \
                AF[mi], BF[ni], acc[mi][ni], 0, 0, 0); \
    } \
    __builtin_amdgcn_s_setprio(0); } while (0)

        // prologue: tile 0 -> buf 0 (issue order [A:5][B0:2][B1:2] = 9)
        STAGE_A(0, 0); STAGE_B(0, 0, 0); STAGE_B(0, 0, 1);
        __builtin_amdgcn_sched_barrier(0);

        for (int t = 0; t < NIT; ++t) {
            const int b = t & 1;
            const char* Cb = LB + b * BUFS;
            const bool st = (t + 1 < NIT);
            short8 bf[4], af[5];

            // ---- half kk0: gate A(t)+B0(t); stage A(t+1)+B0(t+1) ----
            GATE(2);
#pragma unroll
            for (int ni = 0; ni < 4; ++ni)
                bf[ni] = *(const short8*)(Cb + b_base[0] + ni * 1024);
#pragma unroll
            for (int mi = 0; mi < 5; ++mi)
                af[mi] = *(const short8*)(Cb + a_base[0] + mi * 2048);
            if (st) { STAGE_A(b ^ 1, t + 1); STAGE_B(b ^ 1, t + 1, 0); }
            LGKM0;
            MFMA20(af, bf);

            // ---- half kk1: gate B1(t); stage B1(t+1) ----
            if (st) { GATE(7); } else { GATE(0); }
#pragma unroll
            for (int ni = 0; ni < 4; ++ni)
                bf[ni] = *(const short8*)(Cb + b_base[1] + ni * 1024);
#pragma unroll
            for (int mi = 0; mi < 5; ++mi)
                af[mi] = *(const short8*)(Cb + a_base[1] + mi * 2048);
            if (st) STAGE_B(b ^ 1, t + 1, 1);
            LGKM0;
            MFMA20(af, bf);
        }
#undef GATE
#undef LGKM0
#undef MFMA20

        // epilogue: D col = lane&15, row = (lane>>4)*4 + j
        float bias_n[4];
#pragma unroll
        for (int ni = 0; ni < 4; ++ni)
            bias_n[ni] = be[e * FN + n0 + wn * 64 + ni * 16 + frow];

        const int fq4 = fq * 4;
#pragma unroll
        for (int mi = 0; mi < 5; ++mi) {
#pragma unroll
            for (int j = 0; j < 4; ++j) {
                int idx = m0 + wm * H + mi * 16 + fq4 + j;
                if (idx < m_end) {
                    float w = rw[s0 + idx];
                    int oi = ridx[s0 + idx];
                    if (MODE == 0) {
                        float* orow = out + (size_t)(oi >> 1) * FN + n0 + wn * 64 + frow;
#pragma unroll
                        for (int ni = 0; ni < 4; ++ni)
                            atomicAdd(orow + ni * 16, w * (acc[mi][ni][j] + bias_n[ni]));
                    } else if (MODE == 1) {
                        short4v pk;
                        pk.x = (short)f2bf(w * (acc[mi][0][j] + bias_n[0]));
                        pk.y = (short)f2bf(w * (acc[mi][1][j] + bias_n[1]));
                        pk.z = (short)f2bf(w * (acc[mi][2][j] + bias_n[2]));
                        pk.w = (short)f2bf(w * (acc[mi][3][j] + bias_n[3]));
                        *(short4v*)((unsigned short*)ywv + (size_t)oi * FN + n0 + wn * 64 + frow * 4) = pk;
                    } else {
                        f32x4 pk;
                        pk.x = w * (acc[mi][0][j] + bias_n[0]);
                        pk.y = w * (acc[mi][1][j] + bias_n[1]);
                        pk.z = w * (acc[mi][2][j] + bias_n[2]);
                        pk.w = w * (acc[mi][3][j] + bias_n[3]);
                        *(f32x4*)((float*)ywv + (size_t)oi * FN + n0 + wn * 64 + frow * 4) = pk;
                    }
                }
            }
        }
    }
}

// ---------------- combine: out[t] = unperm(yw[2t] + yw[2t+1]), 2 tokens/block
__global__ __launch_bounds__(512) void k_combine_bf(const unsigned short* __restrict__ yw,
                                                    float* __restrict__ out)
{
    __shared__ float ls[2][FN];
    int t = blockIdx.x * 2 + (threadIdx.x >> 8);
    int i = threadIdx.x & 255;
    int half = threadIdx.x >> 8;
    const unsigned* r0 = (const unsigned*)(yw + (size_t)(2 * t) * FN);
    const unsigned* r1 = (const unsigned*)(yw + (size_t)(2 * t + 1) * FN);
    unsigned a0 = r0[2 * i], a1 = r0[2 * i + 1];
    unsigned c0 = r1[2 * i], c1 = r1[2 * i + 1];
    float s0 = bf2f((unsigned short)(a0 & 0xffff)) + bf2f((unsigned short)(c0 & 0xffff));
    float s1 = bf2f((unsigned short)(a0 >> 16))    + bf2f((unsigned short)(c0 >> 16));
    float s2 = bf2f((unsigned short)(a1 & 0xffff)) + bf2f((unsigned short)(c1 & 0xffff));
    float s3 = bf2f((unsigned short)(a1 >> 16))    + bf2f((unsigned short)(c1 >> 16));
    int base = (i >> 4) * 64 + (i & 15);           // 64-col group + frow
    ls[half][base +  0] = s0;
    ls[half][base + 16] = s1;
    ls[half][base + 32] = s2;
    ls[half][base + 48] = s3;
    __syncthreads();
    ((f32x4*)(out + (size_t)t * FN))[i] = ((const f32x4*)&ls[half][0])[i];
}

__global__ __launch_bounds__(512) void k_combine_f32(const float* __restrict__ yw,
                                                     float* __restrict__ out)
{
    __shared__ float ls[2][FN];
    int t = blockIdx.x * 2 + (threadIdx.x >> 8);
    int i = threadIdx.x & 255;
    int half = threadIdx.x >> 8;
    f32x4 a = ((const f32x4*)(yw + (size_t)(2 * t) * FN))[i];
    f32x4 b = ((const f32x4*)(yw + (size_t)(2 * t + 1) * FN))[i];
    f32x4 s = a + b;
    int base = (i >> 4) * 64 + (i & 15);
    ls[half][base +  0] = s.x;
    ls[half][base + 16] = s.y;
    ls[half][base + 32] = s.z;
    ls[half][base + 48] = s.w;
    __syncthreads();
    ((f32x4*)(out + (size_t)t * FN))[i] = ((const f32x4*)&ls[half][0])[i];
}

extern "C" void kernel_launch(void* const* d_in, const int* in_sizes, int n_in,
                              void* d_out, int out_size, void* d_ws, size_t ws_size,
                              hipStream_t stream)
{
    const float* x   = (const float*)d_in[0];
    const float* We  = (const float*)d_in[1];
    const float* beb = (const float*)d_in[2];
    const float* Wg  = (const float*)d_in[3];
    const float* bg  = (const float*)d_in[4];
    float* out = (float*)d_out;

    char* ws = (char*)d_ws;
    unsigned short* xb = (unsigned short*)ws;                        // 16 MB
    unsigned short* Wb = (unsigned short*)(ws + (size_t)(16 << 20)); // 16 MB
    size_t off = (size_t)(32 << 20);
    int*   seg      = (int*)(ws + off);   off += 256;
    int*   blockcnt = (int*)(ws + off);   off += HB * NE * 4;
    int*   meta_e   = (int*)(ws + off);   off += (size_t)NTOK * 2 * 4;
    float* meta_w   = (float*)(ws + off); off += (size_t)NTOK * 2 * 4;
    int*   ridxb    = (int*)(ws + off);   off += (size_t)NTOK * 2 * 4;
    float* rwb      = (float*)(ws + off); off += (size_t)NTOK * 2 * 4;
    void*  yw       = (void*)(ws + ((off + 255) & ~(size_t)255));
    size_t yw_base  = (size_t)((off + 255) & ~(size_t)255);

    int mode;
    if (ws_size >= yw_base + (size_t)NTOK * 2 * FN * 2) mode = 1;       // bf16 yw (32 MB)
    else if (ws_size >= yw_base + (size_t)NTOK * 2 * FN * 4) mode = 2;  // f32 yw (64 MB)
    else mode = 0;                                                      // atomic fallback

    k_prep<<<GATE_BLOCKS + CONV_BLOCKS, 256, 0, stream>>>(x, Wg, bg, We, xb, Wb,
                                                          meta_e, meta_w);
    k_hist<<<HB, 256, 0, stream>>>(meta_e, blockcnt);
    k_scatter<<<HB, 256, 0, stream>>>(meta_e, meta_w, blockcnt, seg, ridxb, rwb);

    const int nblk = NE * (FN / BN) * 16;  // 8 experts x 8 n-tiles x 16 m-tiles = 1024
    if (mode == 1) {
        k_gemm<1><<<nblk, 256, 0, stream>>>(xb, Wb, beb, seg, ridxb, rwb, out, yw);
        k_combine_bf<<<NTOK / 2, 512, 0, stream>>>((const unsigned short*)yw, out);
    } else if (mode == 2) {
        k_gemm<2><<<nblk, 256, 0, stream>>>(xb, Wb, beb, seg, ridxb, rwb, out, yw);
        k_combine_f32<<<NTOK / 2, 512, 0, stream>>>((const float*)yw, out);
    } else {
        hipMemsetAsync(d_out, 0, (size_t)NTOK * FN * 4, stream);
        k_gemm<0><<<nblk, 256, 0, stream>>>(xb, Wb, beb, seg, ridxb, rwb, out, yw);
    }
}

// Round 15
// 80.477 us; speedup vs baseline: 1.1256x; 1.1256x over previous
//
#include <hip/hip_runtime.h>
#include <hip/hip_bf16.h>
#include <stdint.h>

#define NE 8
#define DK 1024
#define FN 1024
#define NTOK 8192

#define BN 256
#define BK 64
#define NIT (DK / BK)
#define H 144            // fixed per-wave rows (2 waves of M, 288-row block)

#define HB 32
#define EPB (NTOK * 2 / HB)

// LDS map per buffer: A [320 rows x 128B] @0 (40960B; rows 288..319 = clamp
// padding), B-kh0 @40960 (16384B), B-kh1 @57344 (16384B); stride 73728B x2.
#define BUFS 73728
#define BOFF 40960

#define GATE_BLOCKS (NTOK / 4)                       // 2048
#define CONV_BLOCKS (NE * FN * DK / 4 / 256)         // 8192

typedef __attribute__((ext_vector_type(4))) float f32x4;
typedef __attribute__((ext_vector_type(8))) short short8;
typedef __attribute__((ext_vector_type(4))) short short4v;

__device__ __forceinline__ unsigned short f2bf(float f) {
    union { float f; unsigned u; } v; v.f = f;
    unsigned r = v.u;
    unsigned lsb = (r >> 16) & 1u;
    r += 0x7fffu + lsb;
    return (unsigned short)(r >> 16);
}
__device__ __forceinline__ float bf2f(unsigned short u) {
    union { unsigned u; float f; } v; v.u = ((unsigned)u) << 16;
    return v.f;
}

// ---------------- fused: gating + x->bf16  |  W->bf16  (one launch) ----------
// Blocks [0, 2048): gate (one wave per token). Blocks [2048, 10240): convw.
__global__ __launch_bounds__(256) void k_prep(const float* __restrict__ x,
    const float* __restrict__ Wg, const float* __restrict__ bg,
    const float* __restrict__ W,
    unsigned short* __restrict__ xb, unsigned short* __restrict__ Wb,
    int* __restrict__ meta_e, float* __restrict__ meta_w)
{
    if (blockIdx.x >= GATE_BLOCKS) {
        // ---- convw part ----
        int i = (blockIdx.x - GATE_BLOCKS) * 256 + threadIdx.x;
        f32x4 v = ((const f32x4*)W)[i];
        short4v b;
        b.x = (short)f2bf(v.x); b.y = (short)f2bf(v.y);
        b.z = (short)f2bf(v.z); b.w = (short)f2bf(v.w);
        ((short4v*)Wb)[i] = b;
        return;
    }

    // ---- gate part ----
    const int lane = threadIdx.x & 63;
    const int t = blockIdx.x * 4 + (threadIdx.x >> 6);

    const f32x4* xr = (const f32x4*)(x + (size_t)t * DK);
    f32x4 xv[4];
#pragma unroll
    for (int c = 0; c < 4; ++c) xv[c] = xr[lane + 64 * c];

    short4v* xbo = (short4v*)(xb + (size_t)t * DK);
#pragma unroll
    for (int c = 0; c < 4; ++c) {
        short4v b;
        b.x = (short)f2bf(xv[c].x); b.y = (short)f2bf(xv[c].y);
        b.z = (short)f2bf(xv[c].z); b.w = (short)f2bf(xv[c].w);
        xbo[lane + 64 * c] = b;
    }

    float acc[NE];
#pragma unroll
    for (int e = 0; e < NE; ++e) {
        const f32x4* wr = (const f32x4*)(Wg + e * DK);
        float a = 0.f;
#pragma unroll
        for (int c = 0; c < 4; ++c) {
            f32x4 wv = wr[lane + 64 * c];
            a += xv[c].x * wv.x + xv[c].y * wv.y + xv[c].z * wv.z + xv[c].w * wv.w;
        }
        acc[e] = a;
    }
#pragma unroll
    for (int e = 0; e < NE; ++e) {
        float a = acc[e];
#pragma unroll
        for (int off = 32; off > 0; off >>= 1) a += __shfl_xor(a, off, 64);
        acc[e] = a;
    }
    if (lane == 0) {
        float v[NE];
#pragma unroll
        for (int e = 0; e < NE; ++e) v[e] = acc[e] + bg[e];
        int b0 = 0; float m0 = v[0];
#pragma unroll
        for (int e = 1; e < NE; ++e) if (v[e] > m0) { m0 = v[e]; b0 = e; }
        int b1 = -1; float m1 = -3.4e38f;
#pragma unroll
        for (int e = 0; e < NE; ++e) if (e != b0 && v[e] > m1) { m1 = v[e]; b1 = e; }
        float r = expf(m1 - m0);
        float s = 1.f + r;
        meta_e[2 * t] = b0; meta_e[2 * t + 1] = b1;
        meta_w[2 * t] = 1.f / s; meta_w[2 * t + 1] = r / s;
    }
}

// ---------------- per-block histogram (LDS atomics only) ---------------------
__global__ __launch_bounds__(256) void k_hist(const int* __restrict__ meta_e,
                                              int* __restrict__ blockcnt)
{
    __shared__ int lh[NE];
    if (threadIdx.x < NE) lh[threadIdx.x] = 0;
    __syncthreads();
    int base = blockIdx.x * EPB;
#pragma unroll
    for (int k = 0; k < EPB / 256; ++k)
        atomicAdd(&lh[meta_e[base + k * 256 + threadIdx.x]], 1);
    __syncthreads();
    if (threadIdx.x < NE) blockcnt[blockIdx.x * NE + threadIdx.x] = lh[threadIdx.x];
}

// ---------------- scatter with inline scan (k_scan folded in) ----------------
// Every block redundantly scans blockcnt (32x8 ints, L2-hot); block 0 also
// writes seg[] for k_gemm. ridx[p] = 2t+k (orig slot), rw[p] = weight.
__global__ __launch_bounds__(256) void k_scatter(const int* __restrict__ meta_e,
    const float* __restrict__ meta_w, const int* __restrict__ blockcnt,
    int* __restrict__ seg, int* __restrict__ ridx, float* __restrict__ rw)
{
    __shared__ int lh[NE];
    __shared__ int bb[NE];
    __shared__ int colsum[NE];
    __shared__ int segstart[NE];
    int tid = threadIdx.x;
    if (tid < NE) {
        lh[tid] = 0;
        int run = 0, mypre = 0;
        for (int b = 0; b < HB; ++b) {
            if (b == (int)blockIdx.x) mypre = run;
            run += blockcnt[b * NE + tid];
        }
        colsum[tid] = run;
        bb[tid] = mypre;            // prefix within column, base added below
    }
    __syncthreads();
    if (tid == 0) {
        int s = 0;
        for (int e = 0; e < NE; ++e) { segstart[e] = s; s += colsum[e]; }
        if (blockIdx.x == 0) {
            int s2 = 0;
            for (int e = 0; e < NE; ++e) { seg[e] = s2; s2 += colsum[e]; }
            seg[NE] = s2;
        }
    }
    __syncthreads();
    if (tid < NE) bb[tid] += segstart[tid];
    __syncthreads();
    int bs = blockIdx.x * EPB;
#pragma unroll
    for (int k = 0; k < EPB / 256; ++k) {
        int i = bs + k * 256 + tid;
        int e = meta_e[i];
        int r = atomicAdd(&lh[e], 1);
        int p = bb[e] + r;
        ridx[p] = i;
        rw[p] = meta_w[i];
    }
}

// ---------------- grouped GEMM: balanced 8-tiles/expert, 4-phase pipeline ----
// CHAMPION (R11/R12, 80.6us total, gemm 43.7-44.1us, 786 TF effective = 93%
// of m248's 848 TF grouped-GEMM reference at K=1024). Register budget is the
// binding constraint: acc[9][4]=144 AGPR + 116 VGPR; 32-bit element offsets
// off SGPR bases; fixed H=144; bias in epilogue; shared B-frag across kk.
// Grid = 8e x 4n x 8mt = 256 blocks, balanced single round, XCD-pinned expert.
template <int MODE>
__global__ __launch_bounds__(512, 2) void k_gemm(const unsigned short* __restrict__ xb,
    const unsigned short* __restrict__ Wb, const float* __restrict__ be,
    const int* __restrict__ seg, const int* __restrict__ ridx,
    const float* __restrict__ rw, float* __restrict__ out, void* __restrict__ ywv)
{
    __shared__ char Lds[2 * BUFS];   // 144 KB

    const int bid = blockIdx.x;
    const int e = bid & 7;                       // XCD-pinned expert
    const int n0 = ((bid >> 3) & 3) * BN;
    const int mt = bid >> 5;                     // 0..7
    const int s0 = seg[e];
    const int L = seg[e + 1] - s0;
    const int lpt = (L + 7) >> 3;                // rows per m-tile
    int m0 = mt * lpt;
    const int m_end = (m0 + lpt < L) ? (m0 + lpt) : L;
    if (m0 >= m_end) return;

    const int tid = threadIdx.x;
    const int lane = tid & 63;
    const int wid = tid >> 6;
    const int wm = wid >> 2, wn = wid & 3;       // 2 x 4 wave grid
    const int frow = lane & 15;
    const int fq = lane >> 4;

    const int bgr = ((tid & 3) ^ ((tid >> 3) & 3)) * 8;
    unsigned boff[2];
#pragma unroll
    for (int c = 0; c < 2; ++c)
        boff[c] = (((unsigned)(e * FN + n0 + c * 128 + (tid >> 2))) << 10) + bgr;

    int b_base[2];
    {
        int r = wn * 64 + frow;
        int sl = fq ^ ((frow >> 1) & 3);
#pragma unroll
        for (int kk = 0; kk < 2; ++kk)
            b_base[kk] = BOFF + kk * 16384 + r * 64 + sl * 16;
    }
    int a_base[2];
#pragma unroll
    for (int kk = 0; kk < 2; ++kk)
        a_base[kk] = (wm * H + frow) * 128 + (((kk * 4 + fq) ^ (frow & 7)) * 16);

    char* LB = (char*)Lds;
    const int ag = ((tid & 7) ^ ((tid >> 3) & 7)) * 8;

    // chunk loop (single iteration unless an expert holds >2304 rows)
    for (; m0 < m_end; m0 += 288) {
        unsigned aoff[5];
#pragma unroll
        for (int c = 0; c < 5; ++c) {
            int r = c * 64 + (tid >> 3);
            int idx = m0 + r; if (idx >= m_end) idx = m_end - 1;
            aoff[c] = (((unsigned)(ridx[s0 + idx] >> 1)) << 10) + ag;
        }

        f32x4 acc[9][4];
#pragma unroll
        for (int i = 0; i < 9; ++i)
#pragma unroll
            for (int j = 0; j < 4; ++j) acc[i][j] = f32x4{0.f, 0.f, 0.f, 0.f};

        auto STAGE_A = [&](int buf, int kt) {
            const unsigned ko = kt * BK;
            char* dst = LB + buf * BUFS + wid * 1024;
#pragma unroll
            for (int c = 0; c < 5; ++c)
                __builtin_amdgcn_global_load_lds(
                    (const __attribute__((address_space(1))) void*)(xb + aoff[c] + ko),
                    (__attribute__((address_space(3))) void*)(dst + c * 8192), 16, 0, 0);
        };
        auto STAGE_B = [&](int buf, int kt, int kh) {
            const unsigned ko = kt * BK + kh * 32;
            char* dst = LB + buf * BUFS + BOFF + kh * 16384 + wid * 1024;
#pragma unroll
            for (int c = 0; c < 2; ++c)
                __builtin_amdgcn_global_load_lds(
                    (const __attribute__((address_space(1))) void*)(Wb + boff[c] + ko),
                    (__attribute__((address_space(3))) void*)(dst + c * 8192), 16, 0, 0);
        };

#define GATE(N) do { asm volatile("s_waitcnt vmcnt(" #N ")" ::: "memory"); \
                     __builtin_amdgcn_s_barrier(); \
                     __builtin_amdgcn_sched_barrier(0); } while (0)
#define BARP  do { __builtin_amdgcn_s_barrier(); \
                   __builtin_amdgcn_sched_barrier(0); } while (0)
#define LGKM0 do { asm volatile("s_waitcnt lgkmcnt(0)" ::: "memory"); \
                   __builtin_amdgcn_sched_barrier(0); } while (0)
#define MFMA45(AF, BF, MLO, CNT) do { \
    __builtin_amdgcn_s_setprio(1); \
    _Pragma("unroll") \
    for (int mi = 0; mi < (CNT); ++mi) { \
        _Pragma("unroll") \
        for (int ni = 0; ni < 4; ++ni) \
            acc[(MLO) + mi][ni] = __builtin_amdgcn_mfma_f32_16x16x32_bf16( \
                AF[mi], BF[ni], acc[(MLO) + mi][ni], 0, 0, 0); \
    } \
    __builtin_amdgcn_s_setprio(0); } while (0)

        STAGE_A(0, 0); STAGE_B(0, 0, 0); STAGE_B(0, 0, 1);
        __builtin_amdgcn_sched_barrier(0);

        // vmcnt proof (in-order retire); per tile issue = [A:5@P0][B0:2@P1][B1:2@P2]
        // P0(t) GATE(2): outstanding A(t)5+B0(t)2+B1(t)2=9 -> retires A+B0.
        // P2(t) GATE(7): outstanding B1(t)2+A(t+1)5+B0(t+1)2=9 -> retires B1(t).
        // Last tile: GATE(0) at P2. WAR: every wave lgkm0s its reads before the
        // next barrier, so post-barrier stages never overwrite in-flight reads.
        for (int t = 0; t < NIT; ++t) {
            const int b = t & 1;
            const char* Cb = LB + b * BUFS;
            const bool st = (t + 1 < NIT);
            short8 bf[4], af[5];

            // ---- P0: gate A(t)+B0(t); kk0 x mi 0-4 ----
            GATE(2);
#pragma unroll
            for (int ni = 0; ni < 4; ++ni)
                bf[ni] = *(const short8*)(Cb + b_base[0] + ni * 1024);
#pragma unroll
            for (int mi = 0; mi < 5; ++mi)
                af[mi] = *(const short8*)(Cb + a_base[0] + mi * 2048);
            if (st) STAGE_A(b ^ 1, t + 1);
            LGKM0;
            MFMA45(af, bf, 0, 5);

            // ---- P1: kk0 x mi 5-8 ----
            BARP;
#pragma unroll
            for (int mi = 0; mi < 4; ++mi)
                af[mi] = *(const short8*)(Cb + a_base[0] + (5 + mi) * 2048);
            if (st) STAGE_B(b ^ 1, t + 1, 0);
            LGKM0;
            MFMA45(af, bf, 5, 4);

            // ---- P2: gate B1(t); kk1 x mi 0-4 (bf reused: b0 frags dead) ----
            if (st) { GATE(7); } else { GATE(0); }
#pragma unroll
            for (int ni = 0; ni < 4; ++ni)
                bf[ni] = *(const short8*)(Cb + b_base[1] + ni * 1024);
#pragma unroll
            for (int mi = 0; mi < 5; ++mi)
                af[mi] = *(const short8*)(Cb + a_base[1] + mi * 2048);
            if (st) STAGE_B(b ^ 1, t + 1, 1);
            LGKM0;
            MFMA45(af, bf, 0, 5);

            // ---- P3: kk1 x mi 5-8 ----
            BARP;
#pragma unroll
            for (int mi = 0; mi < 4; ++mi)
                af[mi] = *(const short8*)(Cb + a_base[1] + (5 + mi) * 2048);
            LGKM0;
            MFMA45(af, bf, 5, 4);
        }
#undef GATE
#undef BARP
#undef LGKM0
#undef MFMA45

        // epilogue: D col = lane&15, row = (lane>>4)*4 + j; bias loaded here
        float bias_n[4];
#pragma unroll
        for (int ni = 0; ni < 4; ++ni)
            bias_n[ni] = be[e * FN + n0 + wn * 64 + ni * 16 + frow];

        const int fq4 = fq * 4;
#pragma unroll
        for (int mi = 0; mi < 9; ++mi) {
#pragma unroll
            for (int j = 0; j < 4; ++j) {
                int lr = mi * 16 + fq4 + j;          // row within wave slice
                int idx = m0 + wm * H + lr;
                if (idx < m_end) {
                    float w = rw[s0 + idx];
                    int oi = ridx[s0 + idx];
                    if (MODE == 0) {
                        float* orow = out + (size_t)(oi >> 1) * FN + n0 + wn * 64 + frow;
#pragma unroll
                        for (int ni = 0; ni < 4; ++ni)
                            atomicAdd(orow + ni * 16, w * (acc[mi][ni][j] + bias_n[ni]));
                    } else if (MODE == 1) {
                        short4v pk;
                        pk.x = (short)f2bf(w * (acc[mi][0][j] + bias_n[0]));
                        pk.y = (short)f2bf(w * (acc[mi][1][j] + bias_n[1]));
                        pk.z = (short)f2bf(w * (acc[mi][2][j] + bias_n[2]));
                        pk.w = (short)f2bf(w * (acc[mi][3][j] + bias_n[3]));
                        *(short4v*)((unsigned short*)ywv + (size_t)oi * FN + n0 + wn * 64 + frow * 4) = pk;
                    } else {
                        f32x4 pk;
                        pk.x = w * (acc[mi][0][j] + bias_n[0]);
                        pk.y = w * (acc[mi][1][j] + bias_n[1]);
                        pk.z = w * (acc[mi][2][j] + bias_n[2]);
                        pk.w = w * (acc[mi][3][j] + bias_n[3]);
                        *(f32x4*)((float*)ywv + (size_t)oi * FN + n0 + wn * 64 + frow * 4) = pk;
                    }
                }
            }
        }
    }
}

// ---------------- combine: out[t] = unperm(yw[2t] + yw[2t+1]) ----------------
// yw cols within each 64-block are permuted: col' = frow*4 + ni  (frow=c&15
// of true col c = wn*64 + ni*16 + frow). LDS pass un-permutes.
__global__ __launch_bounds__(256) void k_combine_bf(const unsigned short* __restrict__ yw,
                                                    float* __restrict__ out)
{
    __shared__ float ls[FN];
    int t = blockIdx.x, i = threadIdx.x;
    const unsigned* r0 = (const unsigned*)(yw + (size_t)(2 * t) * FN);
    const unsigned* r1 = (const unsigned*)(yw + (size_t)(2 * t + 1) * FN);
    unsigned a0 = r0[2 * i], a1 = r0[2 * i + 1];
    unsigned c0 = r1[2 * i], c1 = r1[2 * i + 1];
    float s0 = bf2f((unsigned short)(a0 & 0xffff)) + bf2f((unsigned short)(c0 & 0xffff));
    float s1 = bf2f((unsigned short)(a0 >> 16))    + bf2f((unsigned short)(c0 >> 16));
    float s2 = bf2f((unsigned short)(a1 & 0xffff)) + bf2f((unsigned short)(c1 & 0xffff));
    float s3 = bf2f((unsigned short)(a1 >> 16))    + bf2f((unsigned short)(c1 >> 16));
    int base = (i >> 4) * 64 + (i & 15);           // wn*64 + frow
    ls[base +  0] = s0;
    ls[base + 16] = s1;
    ls[base + 32] = s2;
    ls[base + 48] = s3;
    __syncthreads();
    ((f32x4*)(out + (size_t)t * FN))[i] = ((const f32x4*)ls)[i];
}

__global__ __launch_bounds__(256) void k_combine_f32(const float* __restrict__ yw,
                                                     float* __restrict__ out)
{
    __shared__ float ls[FN];
    int t = blockIdx.x, i = threadIdx.x;
    f32x4 a = ((const f32x4*)(yw + (size_t)(2 * t) * FN))[i];
    f32x4 b = ((const f32x4*)(yw + (size_t)(2 * t + 1) * FN))[i];
    f32x4 s = a + b;
    int base = (i >> 4) * 64 + (i & 15);
    ls[base +  0] = s.x;
    ls[base + 16] = s.y;
    ls[base + 32] = s.z;
    ls[base + 48] = s.w;
    __syncthreads();
    ((f32x4*)(out + (size_t)t * FN))[i] = ((const f32x4*)ls)[i];
}

extern "C" void kernel_launch(void* const* d_in, const int* in_sizes, int n_in,
                              void* d_out, int out_size, void* d_ws, size_t ws_size,
                              hipStream_t stream)
{
    const float* x   = (const float*)d_in[0];
    const float* We  = (const float*)d_in[1];
    const float* beb = (const float*)d_in[2];
    const float* Wg  = (const float*)d_in[3];
    const float* bg  = (const float*)d_in[4];
    float* out = (float*)d_out;

    char* ws = (char*)d_ws;
    unsigned short* xb = (unsigned short*)ws;                        // 16 MB
    unsigned short* Wb = (unsigned short*)(ws + (size_t)(16 << 20)); // 16 MB
    size_t off = (size_t)(32 << 20);
    int*   seg      = (int*)(ws + off);   off += 256;
    int*   blockcnt = (int*)(ws + off);   off += HB * NE * 4;
    int*   meta_e   = (int*)(ws + off);   off += (size_t)NTOK * 2 * 4;
    float* meta_w   = (float*)(ws + off); off += (size_t)NTOK * 2 * 4;
    int*   ridxb    = (int*)(ws + off);   off += (size_t)NTOK * 2 * 4;
    float* rwb      = (float*)(ws + off); off += (size_t)NTOK * 2 * 4;
    void*  yw       = (void*)(ws + ((off + 255) & ~(size_t)255));
    size_t yw_base  = (size_t)((off + 255) & ~(size_t)255);

    // pick epilogue mode from available scratch (host-side, deterministic).
    int mode;
    if (ws_size >= yw_base + (size_t)NTOK * 2 * FN * 2) mode = 1;       // bf16 yw (32 MB)
    else if (ws_size >= yw_base + (size_t)NTOK * 2 * FN * 4) mode = 2;  // f32 yw (64 MB)
    else mode = 0;                                                      // atomic fallback

    k_prep<<<GATE_BLOCKS + CONV_BLOCKS, 256, 0, stream>>>(x, Wg, bg, We, xb, Wb,
                                                          meta_e, meta_w);
    k_hist<<<HB, 256, 0, stream>>>(meta_e, blockcnt);
    k_scatter<<<HB, 256, 0, stream>>>(meta_e, meta_w, blockcnt, seg, ridxb, rwb);

    const int nblk = NE * (FN / BN) * 8;   // 8 experts x 4 n-tiles x 8 m-tiles = 256
    if (mode == 1) {
        k_gemm<1><<<nblk, 512, 0, stream>>>(xb, Wb, beb, seg, ridxb, rwb, out, yw);
        k_combine_bf<<<NTOK, 256, 0, stream>>>((const unsigned short*)yw, out);
    } else if (mode == 2) {
        k_gemm<2><<<nblk, 512, 0, stream>>>(xb, Wb, beb, seg, ridxb, rwb, out, yw);
        k_combine_f32<<<NTOK, 256, 0, stream>>>((const float*)yw, out);
    } else {
        hipMemsetAsync(d_out, 0, (size_t)NTOK * FN * 4, stream);
        k_gemm<0><<<nblk, 512, 0, stream>>>(xb, Wb, beb, seg, ridxb, rwb, out, yw);
    }
}